// Round 1
// baseline (818.429 us; speedup 1.0000x reference)
//
#include <hip/hip_runtime.h>

#define SEQ   2048
#define DK    64
#define QBLK  64
#define KVBLK 32
#define NWAVE 4

typedef __attribute__((ext_vector_type(8))) __bf16 bf16x8;
typedef __attribute__((ext_vector_type(4))) float  f32x4;

__device__ __forceinline__ float grp16_max(float v) {
  v = fmaxf(v, __shfl_xor(v, 1));
  v = fmaxf(v, __shfl_xor(v, 2));
  v = fmaxf(v, __shfl_xor(v, 4));
  v = fmaxf(v, __shfl_xor(v, 8));
  return v;
}
__device__ __forceinline__ float grp16_sum(float v) {
  v += __shfl_xor(v, 1);
  v += __shfl_xor(v, 2);
  v += __shfl_xor(v, 4);
  v += __shfl_xor(v, 8);
  return v;
}

// Flash attention, 4 waves x 16 q-rows, KV tiles of 32.
// mfma_f32_16x16x32_bf16; C/D layout: col=lane&15, row=(lane>>4)*4+reg.
__global__ __launch_bounds__(256, 4)
void sdpa_fwd(const float* __restrict__ Q, const float* __restrict__ K,
              const float* __restrict__ V, const int* __restrict__ M,
              float* __restrict__ O)
{
  // pitches chosen for 16B alignment (ds_read_b128) + <=2-way bank conflicts
  __shared__ __bf16 Klds[KVBLK][72];      // 144B pitch
  __shared__ __bf16 Vt[DK][40];           // 80B pitch (V transposed: Vt[d][k])
  __shared__ __bf16 Plds[NWAVE][16][40];  // 80B pitch, per-wave P tile

  const int tid  = threadIdx.x;
  const int w    = tid >> 6;
  const int lane = tid & 63;
  const int g    = lane >> 4;
  const int li   = lane & 15;

  const int blk = blockIdx.x;
  const int qb  = blk & (SEQ / QBLK - 1);
  const int bh  = blk >> 5;               // (b*H + h)

  const float* Qp = Q + (size_t)bh * SEQ * DK;
  const float* Kp = K + (size_t)bh * SEQ * DK;
  const float* Vp = V + (size_t)bh * SEQ * DK;
  const int*   Mp = M + (size_t)bh * SEQ * SEQ;
  float*       Op = O + (size_t)bh * SEQ * DK;

  const int q0 = qb * QBLK + w * 16;      // this wave's q base

  // ---- Q fragments (scale 1/8 and log2(e) folded in; softmax uses exp2) ----
  bf16x8 qfrag[2];
  {
    const float qs = 0.125f * 1.44269504088896340736f;
    const float* qr = Qp + (size_t)(q0 + li) * DK + g * 8;
    #pragma unroll
    for (int h2 = 0; h2 < 2; ++h2) {
      f32x4 a = *(const f32x4*)(qr + h2 * 32);
      f32x4 b = *(const f32x4*)(qr + h2 * 32 + 4);
      bf16x8 f;
      #pragma unroll
      for (int e = 0; e < 4; ++e) {
        f[e]     = (__bf16)(a[e] * qs);
        f[4 + e] = (__bf16)(b[e] * qs);
      }
      qfrag[h2] = f;
    }
  }

  f32x4 acc[4];
  #pragma unroll
  for (int c = 0; c < 4; ++c) acc[c] = (f32x4){0.f, 0.f, 0.f, 0.f};
  float m_r[4], l_r[4];
  #pragma unroll
  for (int r = 0; r < 4; ++r) { m_r[r] = -__builtin_inff(); l_r[r] = 0.f; }

  for (int kt = 0; kt < SEQ / KVBLK; ++kt) {
    const int kv0 = kt * KVBLK;
    __syncthreads();  // protect Klds/Vt against overwrite (WAR from prev iter)

    // ---- stage K (row-major bf16) and V (transposed) ----
    {
      const int row = tid >> 3;           // 0..31
      const int col = (tid & 7) * 8;      // 0..56
      const float* ks = Kp + (size_t)(kv0 + row) * DK + col;
      f32x4 a = *(const f32x4*)ks;
      f32x4 b = *(const f32x4*)(ks + 4);
      bf16x8 kb;
      #pragma unroll
      for (int e = 0; e < 4; ++e) { kb[e] = (__bf16)a[e]; kb[4 + e] = (__bf16)b[e]; }
      *(bf16x8*)&Klds[row][col] = kb;

      const float* vs = Vp + (size_t)(kv0 + row) * DK + col;
      f32x4 va = *(const f32x4*)vs;
      f32x4 vb = *(const f32x4*)(vs + 4);
      #pragma unroll
      for (int e = 0; e < 4; ++e) {
        Vt[col + e][row]     = (__bf16)va[e];
        Vt[col + 4 + e][row] = (__bf16)vb[e];
      }
    }
    __syncthreads();

    // ---- QK^T: scores for 16 q-rows x 32 k-cols ----
    f32x4 st[2];
    #pragma unroll
    for (int t2 = 0; t2 < 2; ++t2) {
      bf16x8 k0 = *(const bf16x8*)&Klds[t2 * 16 + li][g * 8];
      bf16x8 k1 = *(const bf16x8*)&Klds[t2 * 16 + li][32 + g * 8];
      f32x4 s = (f32x4){0.f, 0.f, 0.f, 0.f};
      s = __builtin_amdgcn_mfma_f32_16x16x32_bf16(qfrag[0], k0, s, 0, 0, 0);
      s = __builtin_amdgcn_mfma_f32_16x16x32_bf16(qfrag[1], k1, s, 0, 0, 0);
      st[t2] = s;
    }

    // ---- mask + online softmax (per lane: 4 q-rows, 1 k-col per tile) ----
    #pragma unroll
    for (int r = 0; r < 4; ++r) {
      const size_t mrow = (size_t)(q0 + 4 * g + r) * SEQ + kv0;
      float s0 = st[0][r];
      float s1 = st[1][r];
      if (Mp[mrow + li])      s0 = -1e9f;   // works for int32 or fp32 0/1 mask
      if (Mp[mrow + 16 + li]) s1 = -1e9f;
      float mx    = grp16_max(fmaxf(s0, s1));
      float mnew  = fmaxf(m_r[r], mx);
      float alpha = __builtin_amdgcn_exp2f(m_r[r] - mnew);
      float p0    = __builtin_amdgcn_exp2f(s0 - mnew);
      float p1    = __builtin_amdgcn_exp2f(s1 - mnew);
      l_r[r] = l_r[r] * alpha + grp16_sum(p0 + p1);
      m_r[r] = mnew;
      acc[0][r] *= alpha;
      acc[1][r] *= alpha;
      acc[2][r] *= alpha;
      acc[3][r] *= alpha;
      Plds[w][4 * g + r][li]      = (__bf16)p0;
      Plds[w][4 * g + r][16 + li] = (__bf16)p1;
    }

    // wave-private P tile: ensure writes land before frag reads
    asm volatile("s_waitcnt lgkmcnt(0)" ::: "memory");
    __builtin_amdgcn_sched_barrier(0);

    // ---- PV: out[q][d] += P[q][k] * V[k][d] ----
    bf16x8 pf = *(const bf16x8*)&Plds[w][li][g * 8];
    #pragma unroll
    for (int c = 0; c < 4; ++c) {
      bf16x8 vf = *(const bf16x8*)&Vt[c * 16 + li][g * 8];
      acc[c] = __builtin_amdgcn_mfma_f32_16x16x32_bf16(pf, vf, acc[c], 0, 0, 0);
    }
  }

  // ---- epilogue: normalize and store fp32 ----
  #pragma unroll
  for (int r = 0; r < 4; ++r) {
    float inv = 1.0f / l_r[r];
    float* orow = Op + (size_t)(q0 + 4 * g + r) * DK + li;
    orow[0]  = acc[0][r] * inv;
    orow[16] = acc[1][r] * inv;
    orow[32] = acc[2][r] * inv;
    orow[48] = acc[3][r] * inv;
  }
}

extern "C" void kernel_launch(void* const* d_in, const int* in_sizes, int n_in,
                              void* d_out, int out_size, void* d_ws, size_t ws_size,
                              hipStream_t stream) {
  const float* Q = (const float*)d_in[0];
  const float* K = (const float*)d_in[1];
  const float* V = (const float*)d_in[2];
  const int*   M = (const int*)d_in[3];
  float*       O = (float*)d_out;

  const int nblocks = 2 * 16 * (SEQ / QBLK);  // B*H*(S/QBLK) = 1024
  sdpa_fwd<<<nblocks, 256, 0, stream>>>(Q, K, V, M, O);
}

// Round 3
// 753.902 us; speedup vs baseline: 1.0856x; 1.0856x over previous
//
#include <hip/hip_runtime.h>

#define SEQ   2048
#define DK    64
#define QBLK  64
#define KVBLK 64
#define NTILE (SEQ / KVBLK)
#define PITCH 72   // bf16 elements; 144B rows, 16B-aligned

typedef __attribute__((ext_vector_type(8))) __bf16 bf16x8;
typedef __attribute__((ext_vector_type(4))) __bf16 bf16x4;
typedef __attribute__((ext_vector_type(4))) float  f32x4;
typedef __attribute__((ext_vector_type(4))) int    i32x4;

__device__ __forceinline__ float grp16_max(float v) {
  v = fmaxf(v, __shfl_xor(v, 1));
  v = fmaxf(v, __shfl_xor(v, 2));
  v = fmaxf(v, __shfl_xor(v, 4));
  v = fmaxf(v, __shfl_xor(v, 8));
  return v;
}
__device__ __forceinline__ float grp16_sum(float v) {
  v += __shfl_xor(v, 1);
  v += __shfl_xor(v, 2);
  v += __shfl_xor(v, 4);
  v += __shfl_xor(v, 8);
  return v;
}

// Flash attention, 4 waves x 16 q-rows, KV tiles of 64.
// K staged at permuted row: Klds[j][d] = K[pi(j)][d], pi(j) = (j&15)*4 + (j>>4),
// so QK^T score col (nt*16+li) <-> kv = li*4+nt => mask loads are int4 and the
// P-tile write is one packed b64 per row, BOTH indexed by true kv index.
// V is staged UNPERMUTED (Vt[d][kv]) so PV contracts P[q][kv] * V[kv][d]
// consistently. (R2 bug: V was also permuted -> P/V index spaces mismatched.)
// K/V/mask for tile t+1 prefetched into registers during compute of tile t.
__global__ __launch_bounds__(256, 2)
void sdpa_fwd(const float* __restrict__ Q, const float* __restrict__ K,
              const float* __restrict__ V, const int* __restrict__ M,
              float* __restrict__ O)
{
  __shared__ __bf16 Klds[KVBLK][PITCH];     // Klds[j][d]  = K[kv0 + pi(j)][d]
  __shared__ __bf16 Vt[DK][PITCH];          // Vt[d][k]    = V[kv0 + k][d]  (true kv)
  __shared__ __bf16 Plds[4][16][PITCH];     // per-wave P tile, indexed by true kv

  const int tid  = threadIdx.x;
  const int w    = tid >> 6;
  const int lane = tid & 63;
  const int g    = lane >> 4;
  const int li   = lane & 15;

  const int blk = blockIdx.x;
  const int qb  = blk & (SEQ / QBLK - 1);
  const int bh  = blk >> 5;                 // b*H + h

  const float* Qp = Q + (size_t)bh * SEQ * DK;
  const float* Kp = K + (size_t)bh * SEQ * DK;
  const float* Vp = V + (size_t)bh * SEQ * DK;
  const int*   Mp = M + (size_t)bh * SEQ * SEQ;
  float*       Op = O + (size_t)bh * SEQ * DK;

  const int q0 = qb * QBLK + w * 16;        // wave's q-row base

  // staging assignment: thread covers K/V row sk, cols [sd, sd+16)
  const int sk = tid >> 2;                  // 0..63
  const int sd = (tid & 3) * 16;            // 0,16,32,48
  const int sj = ((sk & 3) << 4) | (sk >> 2);   // pi^{-1}(sk), K staging row

  // ---- Q fragments (1/sqrt(64) and log2(e) folded; softmax in exp2) ----
  bf16x8 qfrag[2];
  {
    const float qs = 0.125f * 1.44269504088896340736f;
    const float* qr = Qp + (size_t)(q0 + li) * DK + g * 8;
    #pragma unroll
    for (int h2 = 0; h2 < 2; ++h2) {
      f32x4 a = *(const f32x4*)(qr + h2 * 32);
      f32x4 b = *(const f32x4*)(qr + h2 * 32 + 4);
      bf16x8 f;
      #pragma unroll
      for (int e = 0; e < 4; ++e) {
        f[e]     = (__bf16)(a[e] * qs);
        f[4 + e] = (__bf16)(b[e] * qs);
      }
      qfrag[h2] = f;
    }
  }

  f32x4 acc[4];
  #pragma unroll
  for (int c = 0; c < 4; ++c) acc[c] = (f32x4){0.f, 0.f, 0.f, 0.f};
  float m_r[4], l_r[4];
  #pragma unroll
  for (int r = 0; r < 4; ++r) { m_r[r] = -__builtin_inff(); l_r[r] = 0.f; }

  // ---- prefetch registers (tile t+1 in flight during compute of t) ----
  f32x4 kA[4], vA[4];
  i32x4 mA[4];

  // prologue: tile 0
  {
    const float* ks = Kp + (size_t)sk * DK + sd;
    const float* vs = Vp + (size_t)sk * DK + sd;
    #pragma unroll
    for (int i = 0; i < 4; ++i) { kA[i] = *(const f32x4*)(ks + 4 * i); vA[i] = *(const f32x4*)(vs + 4 * i); }
    #pragma unroll
    for (int r = 0; r < 4; ++r)
      mA[r] = *(const i32x4*)(Mp + (size_t)(q0 + 4 * g + r) * SEQ + li * 4);
  }

  for (int kt = 0; kt < NTILE; ++kt) {
    __syncthreads();   // WAR: previous tile's LDS reads complete

    // ---- stage registers -> LDS ----
    {
      bf16x8 klo, khi;
      #pragma unroll
      for (int e = 0; e < 4; ++e) {
        klo[e]     = (__bf16)kA[0][e];
        klo[4 + e] = (__bf16)kA[1][e];
        khi[e]     = (__bf16)kA[2][e];
        khi[4 + e] = (__bf16)kA[3][e];
      }
      *(bf16x8*)&Klds[sj][sd]     = klo;   // K at permuted row
      *(bf16x8*)&Klds[sj][sd + 8] = khi;
      #pragma unroll
      for (int qd = 0; qd < 4; ++qd)
        #pragma unroll
        for (int e = 0; e < 4; ++e)
          Vt[sd + qd * 4 + e][sk] = (__bf16)vA[qd][e];   // V transposed, TRUE kv col
    }

    // keep this tile's mask; issue next tile's loads (in flight during compute)
    i32x4 msk[4];
    #pragma unroll
    for (int r = 0; r < 4; ++r) msk[r] = mA[r];

    if (kt + 1 < NTILE) {
      const int kvn = (kt + 1) * KVBLK;
      const float* ks = Kp + (size_t)(kvn + sk) * DK + sd;
      const float* vs = Vp + (size_t)(kvn + sk) * DK + sd;
      #pragma unroll
      for (int i = 0; i < 4; ++i) { kA[i] = *(const f32x4*)(ks + 4 * i); vA[i] = *(const f32x4*)(vs + 4 * i); }
      #pragma unroll
      for (int r = 0; r < 4; ++r)
        mA[r] = *(const i32x4*)(Mp + (size_t)(q0 + 4 * g + r) * SEQ + kvn + li * 4);
    }

    __syncthreads();   // staged tile visible

    // ---- QK^T: 16 q-rows x 64 score-cols (cols in permuted order) ----
    f32x4 st[4];
    #pragma unroll
    for (int nt = 0; nt < 4; ++nt) {
      bf16x8 b0 = *(const bf16x8*)&Klds[nt * 16 + li][g * 8];
      bf16x8 b1 = *(const bf16x8*)&Klds[nt * 16 + li][32 + g * 8];
      f32x4 s = (f32x4){0.f, 0.f, 0.f, 0.f};
      s = __builtin_amdgcn_mfma_f32_16x16x32_bf16(qfrag[0], b0, s, 0, 0, 0);
      s = __builtin_amdgcn_mfma_f32_16x16x32_bf16(qfrag[1], b1, s, 0, 0, 0);
      st[nt] = s;
    }

    // ---- mask + online softmax; st[nt][r] is kv col li*4+nt of row 4g+r ----
    #pragma unroll
    for (int r = 0; r < 4; ++r) {
      float s0 = msk[r].x ? -1e9f : st[0][r];
      float s1 = msk[r].y ? -1e9f : st[1][r];
      float s2 = msk[r].z ? -1e9f : st[2][r];
      float s3 = msk[r].w ? -1e9f : st[3][r];
      float mx    = grp16_max(fmaxf(fmaxf(s0, s1), fmaxf(s2, s3)));
      float mnew  = fmaxf(m_r[r], mx);
      float alpha = __builtin_amdgcn_exp2f(m_r[r] - mnew);
      float p0 = __builtin_amdgcn_exp2f(s0 - mnew);
      float p1 = __builtin_amdgcn_exp2f(s1 - mnew);
      float p2 = __builtin_amdgcn_exp2f(s2 - mnew);
      float p3 = __builtin_amdgcn_exp2f(s3 - mnew);
      l_r[r] = l_r[r] * alpha + grp16_sum((p0 + p1) + (p2 + p3));
      m_r[r] = mnew;
      acc[0][r] *= alpha;
      acc[1][r] *= alpha;
      acc[2][r] *= alpha;
      acc[3][r] *= alpha;
      bf16x4 pk;
      pk[0] = (__bf16)p0; pk[1] = (__bf16)p1; pk[2] = (__bf16)p2; pk[3] = (__bf16)p3;
      *(bf16x4*)&Plds[w][4 * g + r][li * 4] = pk;   // packed, TRUE kv index
    }

    // wave-private P tile: writes must land before fragment reads
    asm volatile("s_waitcnt lgkmcnt(0)" ::: "memory");
    __builtin_amdgcn_sched_barrier(0);

    // ---- PV: acc[q][d] += P[q][kv] * V[kv][d], both indexed by true kv ----
    bf16x8 pa0 = *(const bf16x8*)&Plds[w][li][g * 8];
    bf16x8 pa1 = *(const bf16x8*)&Plds[w][li][32 + g * 8];
    #pragma unroll
    for (int dt = 0; dt < 4; ++dt) {
      bf16x8 v0 = *(const bf16x8*)&Vt[dt * 16 + li][g * 8];
      bf16x8 v1 = *(const bf16x8*)&Vt[dt * 16 + li][32 + g * 8];
      acc[dt] = __builtin_amdgcn_mfma_f32_16x16x32_bf16(pa0, v0, acc[dt], 0, 0, 0);
      acc[dt] = __builtin_amdgcn_mfma_f32_16x16x32_bf16(pa1, v1, acc[dt], 0, 0, 0);
    }
  }

  // ---- epilogue ----
  #pragma unroll
  for (int r = 0; r < 4; ++r) {
    float inv = 1.0f / l_r[r];
    float* orow = Op + (size_t)(q0 + 4 * g + r) * DK + li;
    #pragma unroll
    for (int dt = 0; dt < 4; ++dt)
      orow[dt * 16] = acc[dt][r] * inv;
  }
}

extern "C" void kernel_launch(void* const* d_in, const int* in_sizes, int n_in,
                              void* d_out, int out_size, void* d_ws, size_t ws_size,
                              hipStream_t stream) {
  const float* Q = (const float*)d_in[0];
  const float* K = (const float*)d_in[1];
  const float* V = (const float*)d_in[2];
  const int*   M = (const int*)d_in[3];
  float*       O = (float*)d_out;

  const int nblocks = 2 * 16 * (SEQ / QBLK);  // 1024
  sdpa_fwd<<<nblocks, 256, 0, stream>>>(Q, K, V, M, O);
}